// Round 9
// baseline (80.516 us; speedup 1.0000x reference)
//
#include <hip/hip_runtime.h>

// TemporalNorm: causal rolling-window (W=128) mean/var norm over time, per (b,d).
// x: [B,T,D] f32, weight/bias: [D] f32, out: [B,T,D] f32.
//
// R9: float4 lanes (fat 16B loads) AND 8 waves/CU (2/SIMD) via CT=64.
// Non-temporal stores keep the output stream out of L2/L3 so the warm-up /
// o-stream re-reads stay cache-absorbed (counters R2's fetch blow-up).
constexpr int Bb  = 32;
constexpr int Tt  = 4096;
constexpr int Dd  = 256;
constexpr int Ww  = 128;
constexpr float EPSF = 1e-5f;

constexpr int CT  = 64;            // time chunk -> 2048 waves = 8 waves/CU
constexpr int NC  = Tt / CT;       // 64 chunks per batch
constexpr int NWG = Bb * NC;       // 2048 blocks, 64 threads each
constexpr int S4  = Dd / 4;        // float4 stride per time step (64)

typedef float f32x4 __attribute__((ext_vector_type(4)));

__device__ __forceinline__ f32x4 rsqrt4(f32x4 v) {
    f32x4 r;
    r.x = rsqrtf(v.x); r.y = rsqrtf(v.y); r.z = rsqrtf(v.z); r.w = rsqrtf(v.w);
    return r;
}

__global__ __launch_bounds__(64)
void TemporalNorm_kernel(const float* __restrict__ x,
                         const float* __restrict__ wgt,
                         const float* __restrict__ bia,
                         float* __restrict__ out) {
    // XCD-contiguous swizzle (NWG % 8 == 0 -> bijective): neighboring chunks
    // of the same series stay on one XCD's L2 (warm/o-stream re-read locality).
    const int i  = blockIdx.x;
    const int lb = (i & 7) * (NWG / 8) + (i >> 3);
    const int b  = lb / NC;
    const int c  = lb % NC;
    const int d4 = threadIdx.x;          // float4 channel group (0..63)
    const int t0 = c * CT;

    const f32x4* __restrict__ xb = reinterpret_cast<const f32x4*>(x   + (size_t)b * Tt * Dd) + d4;
    f32x4*       __restrict__ ob = reinterpret_cast<f32x4*>      (out + (size_t)b * Tt * Dd) + d4;
    const f32x4 w4 = reinterpret_cast<const f32x4*>(wgt)[d4];
    const f32x4 b4 = reinterpret_cast<const f32x4*>(bia)[d4];

    f32x4 s1 = 0.0f, s2 = 0.0f;
    const float rn = 1.0f / (float)Ww;   // exact (1/128)

    if (t0 >= Ww) {
        // ---- steady state: window always full (n = W) ----
        // warm-up over [t0-W, t0): 16 groups? no — 8 loads in flight per group,
        // dual accumulators to shorten the FP dependency chain.
        {
            f32x4 u1 = 0.0f, u2 = 0.0f;
            for (int t = t0 - Ww; t < t0; t += 8) {
                f32x4 a[8];
#pragma unroll
                for (int j = 0; j < 8; ++j) a[j] = xb[(t + j) * S4];
#pragma unroll
                for (int j = 0; j < 8; j += 2) {
                    s1 += a[j];     s2 += a[j] * a[j];
                    u1 += a[j + 1]; u2 += a[j + 1] * a[j + 1];
                }
            }
            s1 += u1; s2 += u2;
        }

        // main loop: 8 outputs per group, 16 independent 16B loads in flight.
        for (int t = t0; t < t0 + CT; t += 8) {
            f32x4 a[8], o[8];
#pragma unroll
            for (int j = 0; j < 8; ++j) a[j] = xb[(t + j) * S4];
#pragma unroll
            for (int j = 0; j < 8; ++j) o[j] = xb[(t + j - Ww) * S4];
#pragma unroll
            for (int j = 0; j < 8; ++j) {
                s1 += a[j] - o[j];
                s2 += (a[j] - o[j]) * (a[j] + o[j]);
                f32x4 loc = s1 * rn;
                f32x4 var = s2 * rn - loc * loc;
                f32x4 r   = (a[j] - loc) * rsqrt4(var + EPSF) * w4 + b4;
                __builtin_nontemporal_store(r, &ob[(t + j) * S4]);
            }
        }
    } else {
        // ---- early chunks (c == 0 or 1, t0+CT <= W): growing window, n = t+1,
        // no subtraction ever (t < W). Warm-up over [0, t0).
        for (int t = 0; t < t0; t += 8) {
            f32x4 a[8];
#pragma unroll
            for (int j = 0; j < 8; ++j) a[j] = xb[(t + j) * S4];
#pragma unroll
            for (int j = 0; j < 8; ++j) { s1 += a[j]; s2 += a[j] * a[j]; }
        }
        for (int t = t0; t < t0 + CT; t += 8) {
            f32x4 a[8];
#pragma unroll
            for (int j = 0; j < 8; ++j) a[j] = xb[(t + j) * S4];
#pragma unroll
            for (int j = 0; j < 8; ++j) {
                s1 += a[j]; s2 += a[j] * a[j];
                float rnv = 1.0f / (float)(t + j + 1);
                f32x4 loc = s1 * rnv;
                f32x4 var = s2 * rnv - loc * loc;
                f32x4 r   = (a[j] - loc) * rsqrt4(var + EPSF) * w4 + b4;
                __builtin_nontemporal_store(r, &ob[(t + j) * S4]);
            }
        }
    }
}

extern "C" void kernel_launch(void* const* d_in, const int* in_sizes, int n_in,
                              void* d_out, int out_size, void* d_ws, size_t ws_size,
                              hipStream_t stream) {
    const float* x   = (const float*)d_in[0];
    const float* wgt = (const float*)d_in[1];
    const float* bia = (const float*)d_in[2];
    float* out = (float*)d_out;

    hipLaunchKernelGGL(TemporalNorm_kernel, dim3(NWG), dim3(64), 0, stream,
                       x, wgt, bia, out);
}

// Round 10
// 64.340 us; speedup vs baseline: 1.2514x; 1.2514x over previous
//
#include <hip/hip_runtime.h>

// TemporalNorm: causal rolling-window (W=128) mean/var norm over time, per (b,d).
// x: [B,T,D] f32, weight/bias: [D] f32, out: [B,T,D] f32.
//
// R10: time-split wave mapping. Lane = (row-group k = lane>>4, chan slot = lane&15).
// One VMEM instruction moves 4 time-rows x 64 channels (1 KB). The serial
// window-scan across the 4 row-groups is closed with a 2-step shfl_up prefix
// of per-row deltas. 32b x 32chunks(CT=128) x 4 dgroups = 4096 waves (16/CU)
// with 16B lanes and the fetch=1.0x chunk shape (CT == W).
constexpr int Bb  = 32;
constexpr int Tt  = 4096;
constexpr int Dd  = 256;
constexpr int Ww  = 128;
constexpr float EPSF = 1e-5f;

constexpr int CT   = 128;            // == W -> warm-up rereads fully cache-absorbed
constexpr int NC   = Tt / CT;        // 32 chunks
constexpr int NDG  = 4;              // 64-channel groups
constexpr int NWG  = Bb * NC * NDG;  // 4096 blocks, 64 threads each
constexpr int SR   = Dd / 4;         // f32x4 stride per row (64)

typedef float f32x4 __attribute__((ext_vector_type(4)));

__device__ __forceinline__ f32x4 rsqrt4(f32x4 v) {
    f32x4 r;
    r.x = rsqrtf(v.x); r.y = rsqrtf(v.y); r.z = rsqrtf(v.z); r.w = rsqrtf(v.w);
    return r;
}
__device__ __forceinline__ f32x4 shfl_up4(f32x4 v, int delta) {
    f32x4 r;
    r.x = __shfl_up(v.x, delta, 64);
    r.y = __shfl_up(v.y, delta, 64);
    r.z = __shfl_up(v.z, delta, 64);
    r.w = __shfl_up(v.w, delta, 64);
    return r;
}
__device__ __forceinline__ f32x4 shfl_xor4(f32x4 v, int mask) {
    f32x4 r;
    r.x = __shfl_xor(v.x, mask, 64);
    r.y = __shfl_xor(v.y, mask, 64);
    r.z = __shfl_xor(v.z, mask, 64);
    r.w = __shfl_xor(v.w, mask, 64);
    return r;
}
__device__ __forceinline__ f32x4 bcast4(f32x4 v, int srcLane) {
    f32x4 r;
    r.x = __shfl(v.x, srcLane, 64);
    r.y = __shfl(v.y, srcLane, 64);
    r.z = __shfl(v.z, srcLane, 64);
    r.w = __shfl(v.w, srcLane, 64);
    return r;
}

__global__ __launch_bounds__(64)
void TemporalNorm_kernel(const float* __restrict__ x,
                         const float* __restrict__ wgt,
                         const float* __restrict__ bia,
                         float* __restrict__ out) {
    // lb layout: ((b*NDG + dg)*NC + c) -> consecutive lb share (b,dg) with
    // adjacent chunks c; XCD-contiguous swizzle (NWG % 8 == 0 -> bijective)
    // keeps those neighbors on one XCD's L2 (o-stream / warm re-read locality).
    const int i  = blockIdx.x;
    const int lb = (i & 7) * (NWG / 8) + (i >> 3);
    const int c    = lb % NC;
    const int rest = lb / NC;
    const int dg   = rest % NDG;
    const int b    = rest / NDG;
    const int t0   = c * CT;

    const int lane = threadIdx.x;
    const int k    = lane >> 4;          // row-group offset (0..3)
    const int cs   = lane & 15;          // f32x4 channel slot within 64-ch group

    const f32x4* __restrict__ xb = reinterpret_cast<const f32x4*>(x   + (size_t)b * Tt * Dd) + dg * 16 + cs;
    f32x4*       __restrict__ ob = reinterpret_cast<f32x4*>      (out + (size_t)b * Tt * Dd) + dg * 16 + cs;
    const f32x4 w4 = reinterpret_cast<const f32x4*>(wgt)[dg * 16 + cs];
    const f32x4 b4 = reinterpret_cast<const f32x4*>(bia)[dg * 16 + cs];

    const float rn = 1.0f / (float)Ww;   // exact (1/128)
    const int bl = 48 + cs;              // broadcast source: group-3 lane, same slot

    f32x4 S1 = 0.0f, S2 = 0.0f;          // window sums at the group's base row

    if (t0 >= Ww) {
        // ---- steady chunk ----
        // warm-up [t0-W, t0): each row-group accumulates its residue class,
        // then a 2-step butterfly sums the 4 class partials into everyone.
        {
            f32x4 c1 = 0.0f, c2 = 0.0f, e1 = 0.0f, e2 = 0.0f;
            for (int t = t0 - Ww; t < t0; t += 8) {
                f32x4 a0 = xb[(t + k) * SR];
                f32x4 a1 = xb[(t + 4 + k) * SR];
                c1 += a0; c2 += a0 * a0;
                e1 += a1; e2 += a1 * a1;
            }
            c1 += e1; c2 += e2;
            c1 += shfl_xor4(c1, 16); c2 += shfl_xor4(c2, 16);
            c1 += shfl_xor4(c1, 32); c2 += shfl_xor4(c2, 32);
            S1 = c1; S2 = c2;
        }
        // main loop: 8 rows per iteration (two 4-row groups), 4 loads in flight.
        for (int t = t0; t < t0 + CT; t += 8) {
            f32x4 a0 = xb[(t + k) * SR];
            f32x4 o0 = xb[(t + k - Ww) * SR];
            f32x4 a1 = xb[(t + 4 + k) * SR];
            f32x4 o1 = xb[(t + 4 + k - Ww) * SR];
#pragma unroll
            for (int g = 0; g < 2; ++g) {
                f32x4 a = (g == 0) ? a0 : a1;
                f32x4 o = (g == 0) ? o0 : o1;
                f32x4 p1 = a - o;
                f32x4 p2 = (a - o) * (a + o);
                // inclusive prefix across the 4 row-groups
                f32x4 u1 = shfl_up4(p1, 16), u2 = shfl_up4(p2, 16);
                if (k >= 1) { p1 += u1; p2 += u2; }
                u1 = shfl_up4(p1, 32); u2 = shfl_up4(p2, 32);
                if (k >= 2) { p1 += u1; p2 += u2; }
                f32x4 s1r = S1 + p1;
                f32x4 s2r = S2 + p2;
                f32x4 loc = s1r * rn;
                f32x4 var = s2r * rn - loc * loc;
                f32x4 res = (a - loc) * rsqrt4(var + EPSF) * w4 + b4;
                ob[(t + 4 * g + k) * SR] = res;
                S1 += bcast4(p1, bl);    // advance base by full 4-row delta
                S2 += bcast4(p2, bl);
            }
        }
    } else {
        // ---- chunk 0: growing window (CT == W so never subtracts) ----
        for (int t = 0; t < CT; t += 8) {
            f32x4 a0 = xb[(t + k) * SR];
            f32x4 a1 = xb[(t + 4 + k) * SR];
#pragma unroll
            for (int g = 0; g < 2; ++g) {
                f32x4 a = (g == 0) ? a0 : a1;
                f32x4 p1 = a;
                f32x4 p2 = a * a;
                f32x4 u1 = shfl_up4(p1, 16), u2 = shfl_up4(p2, 16);
                if (k >= 1) { p1 += u1; p2 += u2; }
                u1 = shfl_up4(p1, 32); u2 = shfl_up4(p2, 32);
                if (k >= 2) { p1 += u1; p2 += u2; }
                f32x4 s1r = S1 + p1;
                f32x4 s2r = S2 + p2;
                float rnv = 1.0f / (float)(t + 4 * g + k + 1);
                f32x4 loc = s1r * rnv;
                f32x4 var = s2r * rnv - loc * loc;
                f32x4 res = (a - loc) * rsqrt4(var + EPSF) * w4 + b4;
                ob[(t + 4 * g + k) * SR] = res;
                S1 += bcast4(p1, bl);
                S2 += bcast4(p2, bl);
            }
        }
    }
}

extern "C" void kernel_launch(void* const* d_in, const int* in_sizes, int n_in,
                              void* d_out, int out_size, void* d_ws, size_t ws_size,
                              hipStream_t stream) {
    const float* x   = (const float*)d_in[0];
    const float* wgt = (const float*)d_in[1];
    const float* bia = (const float*)d_in[2];
    float* out = (float*)d_out;

    hipLaunchKernelGGL(TemporalNorm_kernel, dim3(NWG), dim3(64), 0, stream,
                       x, wgt, bia, out);
}